// Round 1
// baseline (248.888 us; speedup 1.0000x reference)
//
#include <hip/hip_runtime.h>
#include <math.h>

#define IMG_H 96
#define IMG_W 96
#define HW (IMG_H * IMG_W)

// Block: 256 threads = 8 capsule-types (t) x 32 pixels (px, consecutive w).
// Grid: (W/32=3, H=96, N=4).
// Per thread (n,h,w,t): build u_hat[z(32)][o(4)] in registers, run 3 routing
// iterations locally, write 32 output values (coalesced across px lanes).
__global__ __launch_bounds__(256, 2)
void caps_fused_kernel(const float* __restrict__ x,    // (4,4,32,96,96)
                       const float* __restrict__ Wc,   // (4,5,5,1,8) flat 800
                       const float* __restrict__ Wp,   // (4,16,8)    flat 512
                       const float* __restrict__ Wa,   // (4,16,8)    flat 512
                       const float* __restrict__ Ba,   // (4,8)
                       float* __restrict__ out)        // (4,8,32,96,96)
{
    __shared__ float tile[32 * 5 * 36];  // [z][dy][x], x = wb-2 .. wb+33
    __shared__ float wsh[200];           // [k=dy*5+dx][f]

    const int tid = threadIdx.x;
    const int t   = tid >> 5;        // capsule type 0..7
    const int px  = tid & 31;
    const int wb  = blockIdx.x * 32;
    const int h   = blockIdx.y;
    const int n   = blockIdx.z;
    const int w   = wb + px;

    const int zhalf = (t & 1) << 4;  // input z-channel half
    const int fpos  = t >> 1;        // conv filter for pos part (app = 4+fpos)

    float uh[128];                   // u_hat, index [o*32 + z]

    #pragma unroll
    for (int o = 0; o < 4; ++o) {
        __syncthreads();  // previous-o LDS reads complete
        // ---- stage input halo tile + conv weights into LDS ----
        const float* xin = x + (size_t)((n * 4 + o) * 32) * HW;
        for (int idx = tid; idx < 32 * 5 * 36; idx += 256) {
            int z  = idx / 180;
            int r2 = idx - z * 180;
            int dy = r2 / 36;
            int xx = r2 - dy * 36;
            int hh = h + dy - 2;
            int ww = wb + xx - 2;
            float v = 0.0f;
            if ((unsigned)hh < IMG_H && (unsigned)ww < IMG_W)
                v = xin[(size_t)z * HW + hh * IMG_W + ww];
            tile[idx] = v;
        }
        if (tid < 200) wsh[tid] = Wc[o * 200 + tid];
        __syncthreads();

        // ---- 5x5 conv: 16 q-slots, 2 filters each ----
        float rawp[16], rawa[16];
        #pragma unroll
        for (int q = 0; q < 16; ++q) { rawp[q] = 0.0f; rawa[q] = 0.0f; }

        #pragma unroll 1
        for (int dy = 0; dy < 5; ++dy) {
            const float* trow = &tile[zhalf * 180 + dy * 36 + px];
            const float* wrow = &wsh[dy * 40];
            #pragma unroll
            for (int dx = 0; dx < 5; ++dx) {
                float wp = wrow[dx * 8 + fpos];
                float wa = wrow[dx * 8 + 4 + fpos];
                #pragma unroll
                for (int q = 0; q < 16; ++q) {
                    float v = trow[q * 180 + dx];
                    rawp[q] = fmaf(v, wp, rawp[q]);
                    rawa[q] = fmaf(v, wa, rawa[q]);
                }
            }
        }

        const float bias = Ba[o * 8 + t];
        #pragma unroll
        for (int q = 0; q < 16; ++q) rawa[q] += bias;

        // ---- per-(o,t) matrices: column-normalized W_pos + coord, raw W_app ----
        float mn[16], ma[16];
        #pragma unroll
        for (int i = 0; i < 16; ++i) {
            mn[i] = Wp[o * 128 + t * 16 + i];
            ma[i] = Wa[o * 128 + t * 16 + i];
        }
        #pragma unroll
        for (int c = 0; c < 4; ++c) {
            float s = mn[c] * mn[c] + mn[4 + c] * mn[4 + c]
                    + mn[8 + c] * mn[8 + c] + mn[12 + c] * mn[12 + c];
            s = fmaxf(s, 1e-12f);
            float inv = 1.0f / sqrtf(s);
            mn[c] *= inv; mn[4 + c] *= inv; mn[8 + c] *= inv; mn[12 + c] *= inv;
        }
        mn[12] += (float)w * (1.0f / 96.0f);  // [row 3, col 0] += x/W
        mn[13] += (float)h * (1.0f / 96.0f);  // [row 3, col 1] += y/H

        // ---- 4x4 matmuls into u_hat ----
        #pragma unroll
        for (int p0 = 0; p0 < 4; ++p0) {
            #pragma unroll
            for (int c = 0; c < 4; ++c) {
                float sp = rawp[p0*4+0] * mn[c]     + rawp[p0*4+1] * mn[4+c]
                         + rawp[p0*4+2] * mn[8+c]   + rawp[p0*4+3] * mn[12+c];
                float sa = rawa[p0*4+0] * ma[c]     + rawa[p0*4+1] * ma[4+c]
                         + rawa[p0*4+2] * ma[8+c]   + rawa[p0*4+3] * ma[12+c];
                uh[o * 32 + p0 * 4 + c]      = sp;
                uh[o * 32 + 16 + p0 * 4 + c] = sa;
            }
        }
    }

    // ---- dynamic routing: 3 iterations, last one writes output ----
    float bl[4] = {0.0f, 0.0f, 0.0f, 0.0f};

    #pragma unroll
    for (int it = 0; it < 3; ++it) {
        float rr[4];
        #pragma unroll
        for (int o = 0; o < 4; ++o) rr[o] = 1.0f / (1.0f + __expf(-bl[o]));

        // pass 1: reductions (max |p| over pos-z, sum p^2 over app-z)
        float mx = 0.0f, n2 = 0.0f;
        #pragma unroll
        for (int z = 0; z < 16; ++z) {
            float p = uh[z]*rr[0] + uh[32+z]*rr[1] + uh[64+z]*rr[2] + uh[96+z]*rr[3];
            mx = fmaxf(mx, fabsf(p));
        }
        #pragma unroll
        for (int z = 16; z < 32; ++z) {
            float p = uh[z]*rr[0] + uh[32+z]*rr[1] + uh[64+z]*rr[2] + uh[96+z]*rr[3];
            n2 = fmaf(p, p, n2);
        }
        float invm = 1.0f / mx;                    // psquash (no epsilon, as ref)
        float nn   = sqrtf(n2 + 1e-9f);
        float sc   = n2 / ((1.0f + n2) * nn);      // matwo squash scale

        if (it < 2) {
            float sp[4] = {0,0,0,0}, sa[4] = {0,0,0,0};
            #pragma unroll
            for (int z = 0; z < 16; ++z) {
                float p = uh[z]*rr[0] + uh[32+z]*rr[1] + uh[64+z]*rr[2] + uh[96+z]*rr[3];
                float v = p * invm;
                sp[0] = fmaf(uh[z],    v, sp[0]);
                sp[1] = fmaf(uh[32+z], v, sp[1]);
                sp[2] = fmaf(uh[64+z], v, sp[2]);
                sp[3] = fmaf(uh[96+z], v, sp[3]);
            }
            #pragma unroll
            for (int z = 16; z < 32; ++z) {
                float p = uh[z]*rr[0] + uh[32+z]*rr[1] + uh[64+z]*rr[2] + uh[96+z]*rr[3];
                float v = p * sc;
                sa[0] = fmaf(uh[z],    v, sa[0]);
                sa[1] = fmaf(uh[32+z], v, sa[1]);
                sa[2] = fmaf(uh[64+z], v, sa[2]);
                sa[3] = fmaf(uh[96+z], v, sa[3]);
            }
            #pragma unroll
            for (int o = 0; o < 4; ++o) bl[o] += sp[o] * sa[o];
        } else {
            float* op = out + (size_t)((n * 8 + t) * 32) * HW + h * IMG_W + w;
            #pragma unroll
            for (int z = 0; z < 16; ++z) {
                float p = uh[z]*rr[0] + uh[32+z]*rr[1] + uh[64+z]*rr[2] + uh[96+z]*rr[3];
                op[(size_t)z * HW] = p * invm;
            }
            #pragma unroll
            for (int z = 16; z < 32; ++z) {
                float p = uh[z]*rr[0] + uh[32+z]*rr[1] + uh[64+z]*rr[2] + uh[96+z]*rr[3];
                op[(size_t)z * HW] = p * sc;
            }
        }
    }
}

extern "C" void kernel_launch(void* const* d_in, const int* in_sizes, int n_in,
                              void* d_out, int out_size, void* d_ws, size_t ws_size,
                              hipStream_t stream) {
    const float* x  = (const float*)d_in[0];  // input_tensor (4,4,32,96,96)
    const float* Wc = (const float*)d_in[1];  // W_conv (4,5,5,1,8)
    const float* Wp = (const float*)d_in[2];  // W_pos  (4,16,8)
    const float* Wa = (const float*)d_in[3];  // W_app  (4,16,8)
    const float* Ba = (const float*)d_in[4];  // b_app  (4,8)
    float* outp = (float*)d_out;              // (4,8,32,96,96)

    dim3 grid(IMG_W / 32, IMG_H, 4);
    caps_fused_kernel<<<grid, 256, 0, stream>>>(x, Wc, Wp, Wa, Ba, outp);
}

// Round 2
// 224.590 us; speedup vs baseline: 1.1082x; 1.1082x over previous
//
#include <hip/hip_runtime.h>
#include <hip/hip_fp16.h>
#include <math.h>

#define IMG_H 96
#define IMG_W 96
#define HW (IMG_H * IMG_W)
#define SLAB 2888   // 16 z * 180 + 8 pad (bank stagger: 2888 % 32 == 8)

// ---------------- Kernel A: conv 5x5 + 4x4 capsule matmuls -> fp16 u_hat ----
// Block 256 = 32 px * 4 o * 2 tsub. Grid (3 wtiles, 96 h, 4 n).
// Each thread computes 2 capsule types t per parity pass (4 FMA per LDS read).
// ws layout (uint2 = 4 halves): idx = (((n*8+t)*8 + zg)*HW + pix)*4 + o,
//   holding u_hat z = zg*4 + {0..3}.

__device__ __forceinline__ void emit_t(int n, int t, int o, int w, int h, int pix,
                                       const float* rp, const float* ra,
                                       const float* __restrict__ Wp,
                                       const float* __restrict__ Wa,
                                       const float* __restrict__ Ba,
                                       uint2* __restrict__ ws)
{
    float mn[16], ma[16];
    #pragma unroll
    for (int i = 0; i < 16; ++i) {
        mn[i] = Wp[o * 128 + t * 16 + i];
        ma[i] = Wa[o * 128 + t * 16 + i];
    }
    #pragma unroll
    for (int c = 0; c < 4; ++c) {   // column-normalize W_pos (axis=-2)
        float s = mn[c] * mn[c] + mn[4 + c] * mn[4 + c]
                + mn[8 + c] * mn[8 + c] + mn[12 + c] * mn[12 + c];
        float inv = 1.0f / sqrtf(fmaxf(s, 1e-12f));
        mn[c] *= inv; mn[4 + c] *= inv; mn[8 + c] *= inv; mn[12 + c] *= inv;
    }
    mn[12] += (float)w * (1.0f / 96.0f);   // coord add: [row3,col0] += x/W
    mn[13] += (float)h * (1.0f / 96.0f);   // [row3,col1] += y/H
    const float bias = Ba[o * 8 + t];
    const size_t base = (size_t)((n * 8 + t) * 8) * HW;

    #pragma unroll
    for (int p0 = 0; p0 < 4; ++p0) {
        union { uint2 u; __half hh[4]; } pp, pa;
        #pragma unroll
        for (int c = 0; c < 4; ++c) {
            float sp = rp[p0*4+0] * mn[c]    + rp[p0*4+1] * mn[4+c]
                     + rp[p0*4+2] * mn[8+c]  + rp[p0*4+3] * mn[12+c];
            float sa = (ra[p0*4+0]+bias) * ma[c]   + (ra[p0*4+1]+bias) * ma[4+c]
                     + (ra[p0*4+2]+bias) * ma[8+c] + (ra[p0*4+3]+bias) * ma[12+c];
            pp.hh[c] = __float2half(sp);
            pa.hh[c] = __float2half(sa);
        }
        ws[(base + (size_t)p0 * HW + pix) * 4 + o]       = pp.u;  // pos z: zg=p0
        ws[(base + (size_t)(4 + p0) * HW + pix) * 4 + o] = pa.u;  // app z: zg=4+p0
    }
}

__global__ __launch_bounds__(256, 2)
void capsA_kernel(const float* __restrict__ x,    // (4,4,32,96,96)
                  const float* __restrict__ Wc,   // (4,5,5,1,8)
                  const float* __restrict__ Wp,   // (4,16,8)
                  const float* __restrict__ Wa,   // (4,16,8)
                  const float* __restrict__ Ba,   // (4,8)
                  uint2* __restrict__ ws)
{
    __shared__ float tile[4 * SLAB];   // [o][zq 16][dy 5][x 36] (+8 pad per slab)
    __shared__ float wsh[800];         // [o][k 25][f 8]

    const int tid  = threadIdx.x;
    const int o    = tid & 3;
    const int px   = (tid >> 2) & 31;
    const int tsub = tid >> 7;
    const int wb   = blockIdx.x * 32;
    const int h    = blockIdx.y;
    const int n    = blockIdx.z;
    const int w    = wb + px;
    const int pix  = h * IMG_W + w;

    for (int i = tid; i < 800; i += 256) wsh[i] = Wc[i];

    #pragma unroll 1
    for (int parity = 0; parity < 2; ++parity) {
        __syncthreads();
        // stage 4 o-slabs of the z-half used by this parity's 4 t values
        for (int i = tid; i < 4 * 2880; i += 256) {
            int oi = i / 2880;
            int r  = i - oi * 2880;
            int zq = r / 180;
            int r2 = r - zq * 180;
            int dy = r2 / 36;
            int xx = r2 - dy * 36;
            int hh = h + dy - 2;
            int ww = wb + xx - 2;
            float v = 0.0f;
            if ((unsigned)hh < IMG_H && (unsigned)ww < IMG_W)
                v = x[(size_t)((n * 4 + oi) * 32 + parity * 16 + zq) * HW
                      + hh * IMG_W + ww];
            tile[oi * SLAB + r] = v;
        }
        __syncthreads();

        // conv for two t's at once: t_a = parity+4*tsub, t_b = t_a+2
        float rpa[16], rpb[16], raa[16], rab[16];
        #pragma unroll
        for (int q = 0; q < 16; ++q) { rpa[q]=0; rpb[q]=0; raa[q]=0; rab[q]=0; }

        #pragma unroll 1
        for (int dy = 0; dy < 5; ++dy) {
            const float* trow = &tile[o * SLAB + dy * 36 + px];
            const float* wrow = &wsh[o * 200 + dy * 40 + 2 * tsub];
            #pragma unroll
            for (int dx = 0; dx < 5; ++dx) {
                float2 wpv = *(const float2*)(wrow + dx * 8);      // pos filters a,b
                float2 wav = *(const float2*)(wrow + dx * 8 + 4);  // app filters a,b
                #pragma unroll
                for (int q = 0; q < 16; ++q) {
                    float v = trow[q * 180 + dx];
                    rpa[q] = fmaf(v, wpv.x, rpa[q]);
                    rpb[q] = fmaf(v, wpv.y, rpb[q]);
                    raa[q] = fmaf(v, wav.x, raa[q]);
                    rab[q] = fmaf(v, wav.y, rab[q]);
                }
            }
        }
        const int t_a = parity + 4 * tsub;
        emit_t(n, t_a,     o, w, h, pix, rpa, raa, Wp, Wa, Ba, ws);
        emit_t(n, t_a + 2, o, w, h, pix, rpb, rab, Wp, Wa, Ba, ws);
    }
}

// ---------------- Kernel B: dynamic routing, o split across lanes ----------
// Block 256 = 64 px (32 w x 2 h) * 4 o-lanes; o = lane bits [1:0].
// Grid (3 wtiles, 48 hpairs, 32 = n*8+t).
__global__ __launch_bounds__(256, 4)
void capsB_kernel(const uint2* __restrict__ ws, float* __restrict__ out)
{
    const int tid = threadIdx.x;
    const int o   = tid & 3;
    const int px  = tid >> 2;                      // 0..63
    const int w   = blockIdx.x * 32 + (px & 31);
    const int hh  = blockIdx.y * 2 + (px >> 5);
    const int n   = blockIdx.z >> 3;
    const int t   = blockIdx.z & 7;
    const int pix = hh * IMG_W + w;
    const size_t base = (size_t)((n * 8 + t) * 8) * HW;

    float uh[32];
    #pragma unroll
    for (int zg = 0; zg < 8; ++zg) {
        uint2 rv = ws[(base + (size_t)zg * HW + pix) * 4 + o];
        float2 fa = __half22float2(*(__half2*)&rv.x);
        float2 fb = __half22float2(*(__half2*)&rv.y);
        uh[zg*4+0] = fa.x; uh[zg*4+1] = fa.y;
        uh[zg*4+2] = fb.x; uh[zg*4+3] = fb.y;
    }

    float bl = 0.0f;
    float p[32];
    #pragma unroll
    for (int it = 0; it < 3; ++it) {
        float r = 1.0f / (1.0f + __expf(-bl));
        #pragma unroll
        for (int z = 0; z < 32; ++z) {          // p[z] = sum over o (shuffle)
            float c = uh[z] * r;
            c += __shfl_xor(c, 1);
            c += __shfl_xor(c, 2);
            p[z] = c;
        }
        float mx = 0.0f, n2 = 0.0f;
        #pragma unroll
        for (int z = 0; z < 16; ++z) mx = fmaxf(mx, fabsf(p[z]));
        #pragma unroll
        for (int z = 16; z < 32; ++z) n2 = fmaf(p[z], p[z], n2);
        float invm = 1.0f / mx;                  // psquash (no eps, as ref)
        float nn   = sqrtf(n2 + 1e-9f);
        float sc   = n2 / ((1.0f + n2) * nn);    // matwo squash scale

        if (it < 2) {
            float sp = 0.0f, sa = 0.0f;
            #pragma unroll
            for (int z = 0; z < 16; ++z)  sp = fmaf(uh[z], p[z] * invm, sp);
            #pragma unroll
            for (int z = 16; z < 32; ++z) sa = fmaf(uh[z], p[z] * sc, sa);
            bl += sp * sa;
        } else {
            float* op = out + (size_t)((n * 8 + t) * 32) * HW + pix;
            #pragma unroll
            for (int j = 0; j < 8; ++j) {        // lane writes z = o*8+j
                int z = o * 8 + j;
                float scale = (z < 16) ? invm : sc;
                op[(size_t)z * HW] = p[z] * scale;
            }
        }
    }
}

// ---------------- Fallback: round-1 fused kernel (passed @196us) ----------
__global__ __launch_bounds__(256, 2)
void caps_fused_kernel(const float* __restrict__ x, const float* __restrict__ Wc,
                       const float* __restrict__ Wp, const float* __restrict__ Wa,
                       const float* __restrict__ Ba, float* __restrict__ out)
{
    __shared__ float tile[32 * 5 * 36];
    __shared__ float wsh[200];
    const int tid = threadIdx.x;
    const int t = tid >> 5, px = tid & 31;
    const int wb = blockIdx.x * 32, h = blockIdx.y, n = blockIdx.z;
    const int w = wb + px;
    const int zhalf = (t & 1) << 4, fpos = t >> 1;
    float uh[128];
    #pragma unroll
    for (int o = 0; o < 4; ++o) {
        __syncthreads();
        const float* xin = x + (size_t)((n * 4 + o) * 32) * HW;
        for (int idx = tid; idx < 32 * 5 * 36; idx += 256) {
            int z = idx / 180, r2 = idx - z * 180, dy = r2 / 36, xx = r2 - dy * 36;
            int hh = h + dy - 2, ww = wb + xx - 2;
            float v = 0.0f;
            if ((unsigned)hh < IMG_H && (unsigned)ww < IMG_W)
                v = xin[(size_t)z * HW + hh * IMG_W + ww];
            tile[idx] = v;
        }
        if (tid < 200) wsh[tid] = Wc[o * 200 + tid];
        __syncthreads();
        float rawp[16], rawa[16];
        #pragma unroll
        for (int q = 0; q < 16; ++q) { rawp[q] = 0.0f; rawa[q] = 0.0f; }
        #pragma unroll 1
        for (int dy = 0; dy < 5; ++dy) {
            const float* trow = &tile[zhalf * 180 + dy * 36 + px];
            const float* wrow = &wsh[dy * 40];
            #pragma unroll
            for (int dx = 0; dx < 5; ++dx) {
                float wp = wrow[dx * 8 + fpos], wa = wrow[dx * 8 + 4 + fpos];
                #pragma unroll
                for (int q = 0; q < 16; ++q) {
                    float v = trow[q * 180 + dx];
                    rawp[q] = fmaf(v, wp, rawp[q]); rawa[q] = fmaf(v, wa, rawa[q]);
                }
            }
        }
        const float bias = Ba[o * 8 + t];
        #pragma unroll
        for (int q = 0; q < 16; ++q) rawa[q] += bias;
        float mn[16], ma[16];
        #pragma unroll
        for (int i = 0; i < 16; ++i) { mn[i] = Wp[o*128+t*16+i]; ma[i] = Wa[o*128+t*16+i]; }
        #pragma unroll
        for (int c = 0; c < 4; ++c) {
            float s = mn[c]*mn[c]+mn[4+c]*mn[4+c]+mn[8+c]*mn[8+c]+mn[12+c]*mn[12+c];
            float inv = 1.0f / sqrtf(fmaxf(s, 1e-12f));
            mn[c]*=inv; mn[4+c]*=inv; mn[8+c]*=inv; mn[12+c]*=inv;
        }
        mn[12] += (float)w * (1.0f/96.0f); mn[13] += (float)h * (1.0f/96.0f);
        #pragma unroll
        for (int p0 = 0; p0 < 4; ++p0)
            #pragma unroll
            for (int c = 0; c < 4; ++c) {
                float sp = rawp[p0*4]*mn[c]+rawp[p0*4+1]*mn[4+c]+rawp[p0*4+2]*mn[8+c]+rawp[p0*4+3]*mn[12+c];
                float sa = rawa[p0*4]*ma[c]+rawa[p0*4+1]*ma[4+c]+rawa[p0*4+2]*ma[8+c]+rawa[p0*4+3]*ma[12+c];
                uh[o*32+p0*4+c] = sp; uh[o*32+16+p0*4+c] = sa;
            }
    }
    float bl[4] = {0,0,0,0};
    #pragma unroll
    for (int it = 0; it < 3; ++it) {
        float rr[4];
        #pragma unroll
        for (int oo = 0; oo < 4; ++oo) rr[oo] = 1.0f/(1.0f+__expf(-bl[oo]));
        float mx = 0.0f, n2 = 0.0f;
        #pragma unroll
        for (int z = 0; z < 16; ++z) {
            float p = uh[z]*rr[0]+uh[32+z]*rr[1]+uh[64+z]*rr[2]+uh[96+z]*rr[3];
            mx = fmaxf(mx, fabsf(p));
        }
        #pragma unroll
        for (int z = 16; z < 32; ++z) {
            float p = uh[z]*rr[0]+uh[32+z]*rr[1]+uh[64+z]*rr[2]+uh[96+z]*rr[3];
            n2 = fmaf(p, p, n2);
        }
        float invm = 1.0f/mx, nn = sqrtf(n2+1e-9f), sc = n2/((1.0f+n2)*nn);
        if (it < 2) {
            float sp[4] = {0,0,0,0}, sa[4] = {0,0,0,0};
            #pragma unroll
            for (int z = 0; z < 16; ++z) {
                float p = uh[z]*rr[0]+uh[32+z]*rr[1]+uh[64+z]*rr[2]+uh[96+z]*rr[3];
                float v = p*invm;
                sp[0]=fmaf(uh[z],v,sp[0]); sp[1]=fmaf(uh[32+z],v,sp[1]);
                sp[2]=fmaf(uh[64+z],v,sp[2]); sp[3]=fmaf(uh[96+z],v,sp[3]);
            }
            #pragma unroll
            for (int z = 16; z < 32; ++z) {
                float p = uh[z]*rr[0]+uh[32+z]*rr[1]+uh[64+z]*rr[2]+uh[96+z]*rr[3];
                float v = p*sc;
                sa[0]=fmaf(uh[z],v,sa[0]); sa[1]=fmaf(uh[32+z],v,sa[1]);
                sa[2]=fmaf(uh[64+z],v,sa[2]); sa[3]=fmaf(uh[96+z],v,sa[3]);
            }
            #pragma unroll
            for (int oo = 0; oo < 4; ++oo) bl[oo] += sp[oo]*sa[oo];
        } else {
            float* op = out + (size_t)((n*8+t)*32)*HW + h*IMG_W + w;
            #pragma unroll
            for (int z = 0; z < 32; ++z) {
                float p = uh[z]*rr[0]+uh[32+z]*rr[1]+uh[64+z]*rr[2]+uh[96+z]*rr[3];
                op[(size_t)z*HW] = p * ((z < 16) ? invm : sc);
            }
        }
    }
}

extern "C" void kernel_launch(void* const* d_in, const int* in_sizes, int n_in,
                              void* d_out, int out_size, void* d_ws, size_t ws_size,
                              hipStream_t stream) {
    const float* x  = (const float*)d_in[0];
    const float* Wc = (const float*)d_in[1];
    const float* Wp = (const float*)d_in[2];
    const float* Wa = (const float*)d_in[3];
    const float* Ba = (const float*)d_in[4];
    float* outp = (float*)d_out;

    const size_t need = (size_t)4 * 8 * 8 * HW * 4 * sizeof(uint2);  // 75.5 MB
    if (ws_size >= need) {
        capsA_kernel<<<dim3(3, 96, 4), 256, 0, stream>>>(x, Wc, Wp, Wa, Ba,
                                                         (uint2*)d_ws);
        capsB_kernel<<<dim3(3, 48, 32), 256, 0, stream>>>((const uint2*)d_ws, outp);
    } else {
        caps_fused_kernel<<<dim3(3, 96, 4), 256, 0, stream>>>(x, Wc, Wp, Wa, Ba,
                                                              outp);
    }
}